// Round 1
// 5281.540 us; speedup vs baseline: 1.0389x; 1.0389x over previous
//
#include <hip/hip_runtime.h>
#include <stdint.h>

#define B_SZ 4096
#define T_SZ 64
#define ND   128
#define HID  1024
#define PO   256   // ELEMS_B = N_DIM * N_CONTROL

typedef __attribute__((ext_vector_type(8))) short bf16x8;
typedef __attribute__((ext_vector_type(4))) float f32x4;

__device__ __forceinline__ unsigned short f2bf(float x) {
  unsigned int u = __float_as_uint(x);
  u += 0x7fffu + ((u >> 16) & 1u);
  return (unsigned short)(u >> 16);
}
__device__ __forceinline__ float bf2f(unsigned short h) {
  return __uint_as_float(((unsigned int)h) << 16);
}

__device__ __forceinline__ void g2lds(const void* g, void* l) {
  __builtin_amdgcn_global_load_lds(
      (const __attribute__((address_space(1))) unsigned int*)g,
      (__attribute__((address_space(3))) unsigned int*)l, 16, 0, 0);
}

// C = (Ahi+Alo) @ (Bhi+Blo)^T, split bf16x2, fp32 accum, double-buffered LDS
// pipeline (stage k+1 while computing k; ONE barrier per K-iteration).
// A: M x K row-major (hi/lo bf16). B: N x K row-major (pre-transposed weights).
// EPI 1: Z = relu(acc + bias + a0*w1r[n] + a1*w1r[HID+n]) -> split hi/lo
// EPI 2: Z = relu(acc + bias)                             -> split hi/lo
// EPI 3: fused state update: P = acc + bias; pair cols via shfl_xor;
//        s += (P[2j]*a0 + P[2j+1]*a1)*DT; write s, sH(=Zhi), sL(=Zlo), gen.
template <int BM, int BN, int MT, int NT, int EPI>
__global__ __launch_bounds__(256, 1) void gemm_split(
    const unsigned short* __restrict__ Ahi, const unsigned short* __restrict__ Alo,
    const unsigned short* __restrict__ Bhi, const unsigned short* __restrict__ Blo,
    const float* __restrict__ bias, int K, int ldc,
    const float* __restrict__ a_t, const float* __restrict__ w1r,
    unsigned short* __restrict__ Zhi, unsigned short* __restrict__ Zlo,
    float* __restrict__ S, float* __restrict__ gen, int t) {
  constexpr int BK = 32;
  static_assert(BM == BN, "square tiles only");
  constexpr int RA = (BM * BK * 2) / 4096;  // 16B x 256 threads per round
  constexpr int TB = BM * BK * 2;           // bytes per tensor per buffer
  __shared__ __attribute__((aligned(16))) unsigned short AsH[2][BM * BK];
  __shared__ __attribute__((aligned(16))) unsigned short AsL[2][BM * BK];
  __shared__ __attribute__((aligned(16))) unsigned short BsH[2][BN * BK];
  __shared__ __attribute__((aligned(16))) unsigned short BsL[2][BN * BK];

  const int tid  = threadIdx.x;
  const int lane = tid & 63;
  const int wave = tid >> 6;
  const int wm = (wave >> 1) * (MT * 16);
  const int wn = (wave & 1) * (NT * 16);
  const int m0 = blockIdx.x * BM;
  const int n0 = blockIdx.y * BN;
  const size_t Kb = (size_t)K * 2;

  size_t gA[RA], gB[RA];
  int lL[RA];
#pragma unroll
  for (int r = 0; r < RA; ++r) {
    int L = (r * 256 + tid) * 16;  // byte offset in tile; lds dest = wave base + lane*16
    int row = L >> 6;              // BK*2 = 64 bytes per tile row
    int colb = L & 63;
    lL[r] = L;
    gA[r] = (size_t)(m0 + row) * Kb + colb;
    gB[r] = (size_t)(n0 + row) * Kb + colb;
  }

  f32x4 acc[MT][NT] = {};
  const char* Ah = (const char*)Ahi;
  const char* Al = (const char*)Alo;
  const char* Bh = (const char*)Bhi;
  const char* Bl = (const char*)Blo;
  char* asH = (char*)AsH; char* asL = (char*)AsL;
  char* bsH = (char*)BsH; char* bsL = (char*)BsL;

  const int kIt = K / BK;

  // prologue: stage tile 0 into buffer 0
#pragma unroll
  for (int r = 0; r < RA; ++r) {
    g2lds(Ah + gA[r], asH + lL[r]);
    g2lds(Al + gA[r], asL + lL[r]);
    g2lds(Bh + gB[r], bsH + lL[r]);
    g2lds(Bl + gB[r], bsL + lL[r]);
  }

  int cur = 0;
  for (int it = 0; it < kIt; ++it) {
    // compiler emits s_waitcnt vmcnt(0) lgkmcnt(0) before s_barrier:
    // drains buf[cur] staging loads (issued last iter, covered by compute)
    // and guarantees prior-iter ds_reads of the buffer we're about to refill.
    __syncthreads();

    if (it + 1 < kIt) {  // issue next tile's loads into the other buffer
      const size_t kadd = (size_t)(it + 1) * (BK * 2);
      const int lb = (cur ^ 1) * TB;
#pragma unroll
      for (int r = 0; r < RA; ++r) {
        g2lds(Ah + gA[r] + kadd, asH + lb + lL[r]);
        g2lds(Al + gA[r] + kadd, asL + lb + lL[r]);
        g2lds(Bh + gB[r] + kadd, bsH + lb + lL[r]);
        g2lds(Bl + gB[r] + kadd, bsL + lb + lL[r]);
      }
    }

    bf16x8 fa_h[MT], fa_l[MT], fb_h[NT], fb_l[NT];
#pragma unroll
    for (int mt = 0; mt < MT; ++mt) {
      int off = (wm + mt * 16 + (lane & 15)) * BK + (lane >> 4) * 8;
      fa_h[mt] = *(const bf16x8*)&AsH[cur][off];
      fa_l[mt] = *(const bf16x8*)&AsL[cur][off];
    }
#pragma unroll
    for (int nt = 0; nt < NT; ++nt) {
      int off = (wn + nt * 16 + (lane & 15)) * BK + (lane >> 4) * 8;
      fb_h[nt] = *(const bf16x8*)&BsH[cur][off];
      fb_l[nt] = *(const bf16x8*)&BsL[cur][off];
    }
#pragma unroll
    for (int mt = 0; mt < MT; ++mt)
#pragma unroll
      for (int nt = 0; nt < NT; ++nt) {
        acc[mt][nt] = __builtin_amdgcn_mfma_f32_16x16x32_bf16(fa_h[mt], fb_h[nt], acc[mt][nt], 0, 0, 0);
        acc[mt][nt] = __builtin_amdgcn_mfma_f32_16x16x32_bf16(fa_l[mt], fb_h[nt], acc[mt][nt], 0, 0, 0);
        acc[mt][nt] = __builtin_amdgcn_mfma_f32_16x16x32_bf16(fa_h[mt], fb_l[nt], acc[mt][nt], 0, 0, 0);
      }
    cur ^= 1;
  }

  // epilogue: C/D layout col = lane&15, row = (lane>>4)*4 + reg  [m89-verified]
#pragma unroll
  for (int mt = 0; mt < MT; ++mt) {
    const int mb = m0 + wm + mt * 16 + ((lane >> 4) << 2);
    float a0v[4], a1v[4];
    if (EPI == 1 || EPI == 3) {
#pragma unroll
      for (int r = 0; r < 4; ++r) {
        a0v[r] = a_t[(mb + r) * 2];
        a1v[r] = a_t[(mb + r) * 2 + 1];
      }
    }
#pragma unroll
    for (int nt = 0; nt < NT; ++nt) {
      const int n = n0 + wn + nt * 16 + (lane & 15);
      const float bv = bias[n];
      float w0 = 0.f, w1 = 0.f;
      if (EPI == 1) { w0 = w1r[n]; w1 = w1r[HID + n]; }
#pragma unroll
      for (int r = 0; r < 4; ++r) {
        float v = acc[mt][nt][r] + bv;
        if (EPI == 3) {
          // pair adjacent columns: even lane holds P[b][2j], odd holds P[b][2j+1]
          float vx = __shfl_xor(v, 1);
          if (!(lane & 1)) {
            const int b = mb + r;
            const int j = n >> 1;
            const float sv = S[b * ND + j] + (v * a0v[r] + vx * a1v[r]) * 0.1f;
            S[b * ND + j] = sv;
            unsigned short h = f2bf(sv);
            Zhi[b * ND + j] = h;
            Zlo[b * ND + j] = f2bf(sv - bf2f(h));
            gen[(size_t)b * ((T_SZ + 1) * ND) + (size_t)(t + 1) * ND + j] = sv;
          }
        } else {
          if (EPI == 1) v += a0v[r] * w0 + a1v[r] * w1;
          v = fmaxf(v, 0.f);
          unsigned short h = f2bf(v);
          const size_t idx = (size_t)(mb + r) * ldc + n;
          Zhi[idx] = h;
          Zlo[idx] = f2bf(v - bf2f(h));
        }
      }
    }
  }
}

// One-time per launch: transpose+split weights (N x K bf16 hi/lo), transpose
// actions to (T, B, 2), init s = states[:,0,:], write gen[:,0,:].
__global__ void prep_kernel(
    const float* __restrict__ states, const float* __restrict__ actions,
    const float* __restrict__ W1, const float* __restrict__ W2,
    const float* __restrict__ W3,
    unsigned short* __restrict__ W1tH, unsigned short* __restrict__ W1tL,
    unsigned short* __restrict__ W2tH, unsigned short* __restrict__ W2tL,
    unsigned short* __restrict__ W3tH, unsigned short* __restrict__ W3tL,
    float* __restrict__ aT, float* __restrict__ s,
    unsigned short* __restrict__ sH, unsigned short* __restrict__ sL,
    float* __restrict__ gen) {
  const int tid = blockIdx.x * blockDim.x + threadIdx.x;
  const int stride = gridDim.x * blockDim.x;
  for (int i = tid; i < ND * HID; i += stride) {  // W1 rows 0..127 only
    int k = i >> 10, j = i & 1023;
    float v = W1[i];
    unsigned short h = f2bf(v);
    W1tH[j * ND + k] = h;
    W1tL[j * ND + k] = f2bf(v - bf2f(h));
  }
  for (int i = tid; i < HID * HID; i += stride) {
    int k = i >> 10, j = i & 1023;
    float v = W2[i];
    unsigned short h = f2bf(v);
    W2tH[j * HID + k] = h;
    W2tL[j * HID + k] = f2bf(v - bf2f(h));
  }
  for (int i = tid; i < HID * PO; i += stride) {  // W3 cols 256..511 only
    int k = i >> 8, j = i & 255;
    float v = W3[k * 512 + 256 + j];
    unsigned short h = f2bf(v);
    W3tH[j * HID + k] = h;
    W3tL[j * HID + k] = f2bf(v - bf2f(h));
  }
  for (int i = tid; i < B_SZ * T_SZ; i += stride) {  // actions (B,T,2) -> (T,B,2)
    int b = i >> 6, t = i & 63;
    float2 v = ((const float2*)actions)[i];
    ((float2*)aT)[t * B_SZ + b] = v;
  }
  for (int i = tid; i < B_SZ * ND; i += stride) {  // s0, splits, gen[:,0,:]
    int b = i >> 7, n = i & 127;
    float v = states[(size_t)b * (T_SZ * ND) + n];
    s[i] = v;
    unsigned short h = f2bf(v);
    sH[i] = h;
    sL[i] = f2bf(v - bf2f(h));
    gen[(size_t)b * ((T_SZ + 1) * ND) + n] = v;
  }
}

extern "C" void kernel_launch(void* const* d_in, const int* in_sizes, int n_in,
                              void* d_out, int out_size, void* d_ws, size_t ws_size,
                              hipStream_t stream) {
  const float* states  = (const float*)d_in[0];
  const float* actions = (const float*)d_in[1];
  const float* W1 = (const float*)d_in[2];
  const float* b1 = (const float*)d_in[3];
  const float* W2 = (const float*)d_in[4];
  const float* b2 = (const float*)d_in[5];
  const float* W3 = (const float*)d_in[6];
  const float* b3 = (const float*)d_in[7];
  float* gen = (float*)d_out;

  char* w = (char*)d_ws;
  float*          s    = (float*)(w + 0);                          // 2 MB
  unsigned short* sH   = (unsigned short*)(w + (2ull << 20));      // 1 MB
  unsigned short* sL   = (unsigned short*)(w + (3ull << 20));      // 1 MB
  unsigned short* z1H  = (unsigned short*)(w + (4ull << 20));      // 8 MB
  unsigned short* z1L  = (unsigned short*)(w + (12ull << 20));     // 8 MB
  unsigned short* z2H  = (unsigned short*)(w + (20ull << 20));     // 8 MB
  unsigned short* z2L  = (unsigned short*)(w + (28ull << 20));     // 8 MB
  float*          aT   = (float*)(w + (40ull << 20));              // 2 MB
  unsigned short* W1tH = (unsigned short*)(w + (42ull << 20));             // 256 KB
  unsigned short* W1tL = (unsigned short*)(w + (42ull << 20) + 262144);    // 256 KB
  unsigned short* W2tH = (unsigned short*)(w + (43ull << 20));             // 2 MB
  unsigned short* W2tL = (unsigned short*)(w + (45ull << 20));             // 2 MB
  unsigned short* W3tH = (unsigned short*)(w + (47ull << 20));             // 512 KB
  unsigned short* W3tL = (unsigned short*)(w + (47ull << 20) + 524288);    // 512 KB
  // total ws use: 48 MB

  prep_kernel<<<2048, 256, 0, stream>>>(states, actions, W1, W2, W3,
      W1tH, W1tL, W2tH, W2tL, W3tH, W3tL, aT, s, sH, sL, gen);

  const float* w1r = W1 + 128 * 1024;  // W1 rows 128,129 (action columns), fp32
  for (int t = 0; t < 64; ++t) {
    const float* at = aT + (size_t)t * B_SZ * 2;
    // L1: z1 = relu([s,a] @ W1 + b1)   (K=128 MFMA part + exact fp32 rank-2)
    gemm_split<128, 128, 4, 4, 1><<<dim3(32, 8), 256, 0, stream>>>(
        sH, sL, W1tH, W1tL, b1, 128, HID, at, w1r, z1H, z1L,
        (float*)nullptr, (float*)nullptr, 0);
    // L2: z2 = relu(z1 @ W2 + b2)
    gemm_split<128, 128, 4, 4, 2><<<dim3(32, 8), 256, 0, stream>>>(
        z1H, z1L, W2tH, W2tL, b2, HID, HID, (const float*)nullptr,
        (const float*)nullptr, z2H, z2L, (float*)nullptr, (float*)nullptr, 0);
    // L3 + fused state update: P = z2 @ W3[:,256:512] + b3[256:512];
    // s += (P[:,2j]*a0 + P[:,2j+1]*a1)*DT; writes s, sH, sL, gen[:,t+1,:]
    gemm_split<64, 64, 2, 2, 3><<<dim3(64, 4), 256, 0, stream>>>(
        z2H, z2L, W3tH, W3tL, b3 + 256, HID, PO, at, (const float*)nullptr,
        sH, sL, s, gen, t);
  }
}

// Round 3
// 4482.388 us; speedup vs baseline: 1.2241x; 1.1783x over previous
//
#include <hip/hip_runtime.h>
#include <stdint.h>

#define B_SZ 4096
#define T_SZ 64
#define ND   128
#define HID  1024
#define PO   256   // ELEMS_B = N_DIM * N_CONTROL

typedef __attribute__((ext_vector_type(8))) short bf16x8;
typedef __attribute__((ext_vector_type(4))) float f32x4;

__device__ __forceinline__ unsigned short f2bf(float x) {
  unsigned int u = __float_as_uint(x);
  u += 0x7fffu + ((u >> 16) & 1u);
  return (unsigned short)(u >> 16);
}
__device__ __forceinline__ float bf2f(unsigned short h) {
  return __uint_as_float(((unsigned int)h) << 16);
}

__device__ __forceinline__ void g2lds(const void* g, void* l) {
  __builtin_amdgcn_global_load_lds(
      (const __attribute__((address_space(1))) unsigned int*)g,
      (__attribute__((address_space(3))) unsigned int*)l, 16, 0, 0);
}

// C = (Ahi+Alo) @ (Bhi+Blo)^T, split bf16x2, fp32 accum, double-buffered LDS
// pipeline (stage k+1 while computing k; ONE barrier per K-iteration).
// A: M x K row-major (hi/lo bf16). B: N x K row-major (pre-transposed weights).
// Grid sized for >=2 blocks/CU so cross-wave overlap hides staging/ds_read.
// EPI 1: Z = relu(acc + bias + a0*w1r[n] + a1*w1r[HID+n]) -> split hi/lo
// EPI 2: Z = relu(acc + bias)                             -> split hi/lo
// EPI 3: fused state update: P = acc + bias; pair cols via shfl_xor;
//        s += (P[2j]*a0 + P[2j+1]*a1)*DT; write s, sH(=Zhi), sL(=Zlo), gen.
template <int BM, int BN, int MT, int NT, int EPI>
__global__ __launch_bounds__(256, 2) void gemm_split(
    const unsigned short* __restrict__ Ahi, const unsigned short* __restrict__ Alo,
    const unsigned short* __restrict__ Bhi, const unsigned short* __restrict__ Blo,
    const float* __restrict__ bias, int K, int ldc,
    const float* __restrict__ a_t, const float* __restrict__ w1r,
    unsigned short* __restrict__ Zhi, unsigned short* __restrict__ Zlo,
    float* __restrict__ S, float* __restrict__ gen, int t) {
  constexpr int BK = 32;
  constexpr int ABYTES = BM * BK * 2;   // bytes per A tensor per buffer
  constexpr int BBYTES = BN * BK * 2;   // bytes per B tensor per buffer
  constexpr int RA = (ABYTES + 4095) / 4096;  // 16B x 256 threads per round
  constexpr int RB = (BBYTES + 4095) / 4096;
  constexpr int WN_WAVES = BN / (NT * 16);
  constexpr int WM_WAVES = BM / (MT * 16);
  static_assert(WM_WAVES * WN_WAVES == 4, "4 waves per block");
  __shared__ __attribute__((aligned(16))) unsigned short AsH[2][BM * BK];
  __shared__ __attribute__((aligned(16))) unsigned short AsL[2][BM * BK];
  __shared__ __attribute__((aligned(16))) unsigned short BsH[2][BN * BK];
  __shared__ __attribute__((aligned(16))) unsigned short BsL[2][BN * BK];

  const int tid  = threadIdx.x;
  const int lane = tid & 63;
  const int wave = tid >> 6;
  const int wm = (wave / WN_WAVES) * (MT * 16);
  const int wn = (wave % WN_WAVES) * (NT * 16);
  const int m0 = blockIdx.x * BM;
  const int n0 = blockIdx.y * BN;
  const size_t Kb = (size_t)K * 2;

  size_t gA[RA], gB[RB];
  int lA[RA], lB[RB];
#pragma unroll
  for (int r = 0; r < RA; ++r) {
    int L = (r * 256 + tid) * 16;  // byte offset in A tile
    lA[r] = L;
    gA[r] = (size_t)(m0 + (L >> 6)) * Kb + (L & 63);  // BK*2=64 B per tile row
  }
#pragma unroll
  for (int r = 0; r < RB; ++r) {
    int L = (r * 256 + tid) * 16;
    lB[r] = L;
    gB[r] = (size_t)(n0 + (L >> 6)) * Kb + (L & 63);
  }

  f32x4 acc[MT][NT] = {};
  const char* Ah = (const char*)Ahi;
  const char* Al = (const char*)Alo;
  const char* Bh = (const char*)Bhi;
  const char* Bl = (const char*)Blo;
  char* asH = (char*)AsH; char* asL = (char*)AsL;
  char* bsH = (char*)BsH; char* bsL = (char*)BsL;

  const int kIt = K / BK;

  // prologue: stage tile 0 into buffer 0 (guards are wave-uniform)
#pragma unroll
  for (int r = 0; r < RA; ++r)
    if (ABYTES % 4096 == 0 || lA[r] < ABYTES) {
      g2lds(Ah + gA[r], asH + lA[r]);
      g2lds(Al + gA[r], asL + lA[r]);
    }
#pragma unroll
  for (int r = 0; r < RB; ++r)
    if (BBYTES % 4096 == 0 || lB[r] < BBYTES) {
      g2lds(Bh + gB[r], bsH + lB[r]);
      g2lds(Bl + gB[r], bsL + lB[r]);
    }

  int cur = 0;
  for (int it = 0; it < kIt; ++it) {
    // compiler emits s_waitcnt vmcnt(0) lgkmcnt(0) before s_barrier:
    // drains buf[cur] staging loads (issued last iter, covered by compute)
    // and guarantees prior-iter ds_reads of the buffer we're about to refill.
    __syncthreads();

    if (it + 1 < kIt) {  // issue next tile's loads into the other buffer
      const size_t kadd = (size_t)(it + 1) * (BK * 2);
      const int la = (cur ^ 1) * ABYTES;
      const int lb = (cur ^ 1) * BBYTES;
#pragma unroll
      for (int r = 0; r < RA; ++r)
        if (ABYTES % 4096 == 0 || lA[r] < ABYTES) {
          g2lds(Ah + gA[r] + kadd, asH + la + lA[r]);
          g2lds(Al + gA[r] + kadd, asL + la + lA[r]);
        }
#pragma unroll
      for (int r = 0; r < RB; ++r)
        if (BBYTES % 4096 == 0 || lB[r] < BBYTES) {
          g2lds(Bh + gB[r] + kadd, bsH + lb + lB[r]);
          g2lds(Bl + gB[r] + kadd, bsL + lb + lB[r]);
        }
    }

    bf16x8 fa_h[MT], fa_l[MT], fb_h[NT], fb_l[NT];
#pragma unroll
    for (int mt = 0; mt < MT; ++mt) {
      int off = (wm + mt * 16 + (lane & 15)) * BK + (lane >> 4) * 8;
      fa_h[mt] = *(const bf16x8*)&AsH[cur][off];
      fa_l[mt] = *(const bf16x8*)&AsL[cur][off];
    }
#pragma unroll
    for (int nt = 0; nt < NT; ++nt) {
      int off = (wn + nt * 16 + (lane & 15)) * BK + (lane >> 4) * 8;
      fb_h[nt] = *(const bf16x8*)&BsH[cur][off];
      fb_l[nt] = *(const bf16x8*)&BsL[cur][off];
    }
#pragma unroll
    for (int mt = 0; mt < MT; ++mt)
#pragma unroll
      for (int nt = 0; nt < NT; ++nt) {
        acc[mt][nt] = __builtin_amdgcn_mfma_f32_16x16x32_bf16(fa_h[mt], fb_h[nt], acc[mt][nt], 0, 0, 0);
        acc[mt][nt] = __builtin_amdgcn_mfma_f32_16x16x32_bf16(fa_l[mt], fb_h[nt], acc[mt][nt], 0, 0, 0);
        acc[mt][nt] = __builtin_amdgcn_mfma_f32_16x16x32_bf16(fa_h[mt], fb_l[nt], acc[mt][nt], 0, 0, 0);
      }
    cur ^= 1;
  }

  // epilogue: C/D layout col = lane&15, row = (lane>>4)*4 + reg  [m89-verified]
#pragma unroll
  for (int mt = 0; mt < MT; ++mt) {
    const int mb = m0 + wm + mt * 16 + ((lane >> 4) << 2);
    float a0v[4], a1v[4];
    if (EPI == 1 || EPI == 3) {
#pragma unroll
      for (int r = 0; r < 4; ++r) {
        a0v[r] = a_t[(mb + r) * 2];
        a1v[r] = a_t[(mb + r) * 2 + 1];
      }
    }
#pragma unroll
    for (int nt = 0; nt < NT; ++nt) {
      const int n = n0 + wn + nt * 16 + (lane & 15);
      const float bv = bias[n];
      float w0 = 0.f, w1 = 0.f;
      if (EPI == 1) { w0 = w1r[n]; w1 = w1r[HID + n]; }
#pragma unroll
      for (int r = 0; r < 4; ++r) {
        float v = acc[mt][nt][r] + bv;
        if (EPI == 3) {
          // pair adjacent columns: even lane holds P[b][2j], odd holds P[b][2j+1]
          float vx = __shfl_xor(v, 1);
          if (!(lane & 1)) {
            const int b = mb + r;
            const int j = n >> 1;
            const float sv = S[b * ND + j] + (v * a0v[r] + vx * a1v[r]) * 0.1f;
            S[b * ND + j] = sv;
            unsigned short h = f2bf(sv);
            Zhi[b * ND + j] = h;
            Zlo[b * ND + j] = f2bf(sv - bf2f(h));
            gen[(size_t)b * ((T_SZ + 1) * ND) + (size_t)(t + 1) * ND + j] = sv;
          }
        } else {
          if (EPI == 1) v += a0v[r] * w0 + a1v[r] * w1;
          v = fmaxf(v, 0.f);
          unsigned short h = f2bf(v);
          const size_t idx = (size_t)(mb + r) * ldc + n;
          Zhi[idx] = h;
          Zlo[idx] = f2bf(v - bf2f(h));
        }
      }
    }
  }
}

// One-time per launch: transpose+split weights (N x K bf16 hi/lo), transpose
// actions to (T, B, 2), init s = states[:,0,:], write gen[:,0,:].
__global__ void prep_kernel(
    const float* __restrict__ states, const float* __restrict__ actions,
    const float* __restrict__ W1, const float* __restrict__ W2,
    const float* __restrict__ W3,
    unsigned short* __restrict__ W1tH, unsigned short* __restrict__ W1tL,
    unsigned short* __restrict__ W2tH, unsigned short* __restrict__ W2tL,
    unsigned short* __restrict__ W3tH, unsigned short* __restrict__ W3tL,
    float* __restrict__ aT, float* __restrict__ s,
    unsigned short* __restrict__ sH, unsigned short* __restrict__ sL,
    float* __restrict__ gen) {
  const int tid = blockIdx.x * blockDim.x + threadIdx.x;
  const int stride = gridDim.x * blockDim.x;
  for (int i = tid; i < ND * HID; i += stride) {  // W1 rows 0..127 only
    int k = i >> 10, j = i & 1023;
    float v = W1[i];
    unsigned short h = f2bf(v);
    W1tH[j * ND + k] = h;
    W1tL[j * ND + k] = f2bf(v - bf2f(h));
  }
  for (int i = tid; i < HID * HID; i += stride) {
    int k = i >> 10, j = i & 1023;
    float v = W2[i];
    unsigned short h = f2bf(v);
    W2tH[j * HID + k] = h;
    W2tL[j * HID + k] = f2bf(v - bf2f(h));
  }
  for (int i = tid; i < HID * PO; i += stride) {  // W3 cols 256..511 only
    int k = i >> 8, j = i & 255;
    float v = W3[k * 512 + 256 + j];
    unsigned short h = f2bf(v);
    W3tH[j * HID + k] = h;
    W3tL[j * HID + k] = f2bf(v - bf2f(h));
  }
  for (int i = tid; i < B_SZ * T_SZ; i += stride) {  // actions (B,T,2) -> (T,B,2)
    int b = i >> 6, t = i & 63;
    float2 v = ((const float2*)actions)[i];
    ((float2*)aT)[t * B_SZ + b] = v;
  }
  for (int i = tid; i < B_SZ * ND; i += stride) {  // s0, splits, gen[:,0,:]
    int b = i >> 7, n = i & 127;
    float v = states[(size_t)b * (T_SZ * ND) + n];
    s[i] = v;
    unsigned short h = f2bf(v);
    sH[i] = h;
    sL[i] = f2bf(v - bf2f(h));
    gen[(size_t)b * ((T_SZ + 1) * ND) + n] = v;
  }
}

extern "C" void kernel_launch(void* const* d_in, const int* in_sizes, int n_in,
                              void* d_out, int out_size, void* d_ws, size_t ws_size,
                              hipStream_t stream) {
  const float* states  = (const float*)d_in[0];
  const float* actions = (const float*)d_in[1];
  const float* W1 = (const float*)d_in[2];
  const float* b1 = (const float*)d_in[3];
  const float* W2 = (const float*)d_in[4];
  const float* b2 = (const float*)d_in[5];
  const float* W3 = (const float*)d_in[6];
  const float* b3 = (const float*)d_in[7];
  float* gen = (float*)d_out;

  char* w = (char*)d_ws;
  float*          s    = (float*)(w + 0);                          // 2 MB
  unsigned short* sH   = (unsigned short*)(w + (2ull << 20));      // 1 MB
  unsigned short* sL   = (unsigned short*)(w + (3ull << 20));      // 1 MB
  unsigned short* z1H  = (unsigned short*)(w + (4ull << 20));      // 8 MB
  unsigned short* z1L  = (unsigned short*)(w + (12ull << 20));     // 8 MB
  unsigned short* z2H  = (unsigned short*)(w + (20ull << 20));     // 8 MB
  unsigned short* z2L  = (unsigned short*)(w + (28ull << 20));     // 8 MB
  float*          aT   = (float*)(w + (40ull << 20));              // 2 MB
  unsigned short* W1tH = (unsigned short*)(w + (42ull << 20));             // 256 KB
  unsigned short* W1tL = (unsigned short*)(w + (42ull << 20) + 262144);    // 256 KB
  unsigned short* W2tH = (unsigned short*)(w + (43ull << 20));             // 2 MB
  unsigned short* W2tL = (unsigned short*)(w + (45ull << 20));             // 2 MB
  unsigned short* W3tH = (unsigned short*)(w + (47ull << 20));             // 512 KB
  unsigned short* W3tL = (unsigned short*)(w + (47ull << 20) + 524288);    // 512 KB
  // total ws use: 48 MB

  prep_kernel<<<2048, 256, 0, stream>>>(states, actions, W1, W2, W3,
      W1tH, W1tL, W2tH, W2tL, W3tH, W3tL, aT, s, sH, sL, gen);

  const float* w1r = W1 + 128 * 1024;  // W1 rows 128,129 (action columns), fp32
  for (int t = 0; t < 64; ++t) {
    const float* at = aT + (size_t)t * B_SZ * 2;
    // L1: z1 = relu([s,a] @ W1 + b1)   (K=128 MFMA part + exact fp32 rank-2)
    gemm_split<128, 64, 4, 2, 1><<<dim3(32, 16), 256, 0, stream>>>(
        sH, sL, W1tH, W1tL, b1, 128, HID, at, w1r, z1H, z1L,
        (float*)nullptr, (float*)nullptr, 0);
    // L2: z2 = relu(z1 @ W2 + b2)
    gemm_split<128, 64, 4, 2, 2><<<dim3(32, 16), 256, 0, stream>>>(
        z1H, z1L, W2tH, W2tL, b2, HID, HID, (const float*)nullptr,
        (const float*)nullptr, z2H, z2L, (float*)nullptr, (float*)nullptr, 0);
    // L3 + fused state update: P = z2 @ W3[:,256:512] + b3[256:512];
    // s += (P[:,2j]*a0 + P[:,2j+1]*a1)*DT; writes s, sH, sL, gen[:,t+1,:]
    gemm_split<64, 32, 2, 1, 3><<<dim3(64, 8), 256, 0, stream>>>(
        z2H, z2L, W3tH, W3tL, b3 + 256, HID, PO, at, (const float*)nullptr,
        sH, sL, s, gen, t);
  }
}

// Round 5
// 4423.195 us; speedup vs baseline: 1.2405x; 1.0134x over previous
//
#include <hip/hip_runtime.h>
#include <stdint.h>

#define B_SZ 4096
#define T_SZ 64
#define ND   128
#define HID  1024
#define PO   256   // ELEMS_B = N_DIM * N_CONTROL

typedef __attribute__((ext_vector_type(8))) short bf16x8;
typedef __attribute__((ext_vector_type(4))) float f32x4;

__device__ __forceinline__ unsigned short f2bf(float x) {
  unsigned int u = __float_as_uint(x);
  u += 0x7fffu + ((u >> 16) & 1u);
  return (unsigned short)(u >> 16);
}
__device__ __forceinline__ float bf2f(unsigned short h) {
  return __uint_as_float(((unsigned int)h) << 16);
}

__device__ __forceinline__ void g2lds(const void* g, void* l) {
  __builtin_amdgcn_global_load_lds(
      (const __attribute__((address_space(1))) unsigned int*)g,
      (__attribute__((address_space(3))) unsigned int*)l, 16, 0, 0);
}

// C = (Ahi+Alo) @ (Bhi+Blo)^T, split bf16x2, fp32 accum, double-buffered LDS
// pipeline (stage k+1 while computing k; ONE barrier per K-iteration).
// A: M x K row-major (hi/lo bf16). B: N x K row-major (pre-transposed weights).
// LDS bank-conflict fix (T2): 16B-chunk index XOR'd with (row>>1)&3.
// Row-major [row][32] bf16 rows are 64 B; unswizzled, the 8 even rows of each
// 16-lane fragment group hit the same 4 banks (8-way, 2.94x). The XOR spreads
// them across all 8 bank-groups (residual 2-way = free). global_load_lds
// writes LDS linearly, so the same involution is applied to the per-lane
// GLOBAL source address (within each row's 64B k-window; coalescing intact)
// and to the ds_read offset — both-sides-or-neither (rule #21).
// EPI 1: Z = relu(acc + bias + a0*w1r[n] + a1*w1r[HID+n]) -> split hi/lo
// EPI 2: Z = relu(acc + bias)                             -> split hi/lo
// EPI 3: fused state update: P = acc + bias; pair cols via shfl_xor;
//        s += (P[2j]*a0 + P[2j+1]*a1)*DT; write s, sH(=Zhi), sL(=Zlo), gen.
template <int BM, int BN, int MT, int NT, int EPI>
__global__ __launch_bounds__(256, 2) void gemm_split(
    const unsigned short* __restrict__ Ahi, const unsigned short* __restrict__ Alo,
    const unsigned short* __restrict__ Bhi, const unsigned short* __restrict__ Blo,
    const float* __restrict__ bias, int K, int ldc,
    const float* __restrict__ a_t, const float* __restrict__ w1r,
    unsigned short* __restrict__ Zhi, unsigned short* __restrict__ Zlo,
    float* __restrict__ S, float* __restrict__ gen, int t) {
  constexpr int BK = 32;
  constexpr int ABYTES = BM * BK * 2;   // bytes per A tensor per buffer
  constexpr int BBYTES = BN * BK * 2;   // bytes per B tensor per buffer
  constexpr int RA = (ABYTES + 4095) / 4096;  // 16B x 256 threads per round
  constexpr int RB = (BBYTES + 4095) / 4096;
  constexpr int WN_WAVES = BN / (NT * 16);
  constexpr int WM_WAVES = BM / (MT * 16);
  static_assert(WM_WAVES * WN_WAVES == 4, "4 waves per block");
  __shared__ __attribute__((aligned(16))) unsigned short AsH[2][BM * BK];
  __shared__ __attribute__((aligned(16))) unsigned short AsL[2][BM * BK];
  __shared__ __attribute__((aligned(16))) unsigned short BsH[2][BN * BK];
  __shared__ __attribute__((aligned(16))) unsigned short BsL[2][BN * BK];

  const int tid  = threadIdx.x;
  const int lane = tid & 63;
  const int wave = tid >> 6;
  const int wm = (wave / WN_WAVES) * (MT * 16);
  const int wn = (wave % WN_WAVES) * (NT * 16);
  const int m0 = blockIdx.x * BM;
  const int n0 = blockIdx.y * BN;
  const size_t Kb = (size_t)K * 2;

  size_t gA[RA], gB[RB];
  int lA[RA], lB[RB];
#pragma unroll
  for (int r = 0; r < RA; ++r) {
    int L = (r * 256 + tid) * 16;  // linear byte offset in A tile (LDS dest)
    lA[r] = L;
    int row = L >> 6;              // BK*2 = 64 B per tile row
    int sc  = ((L >> 4) & 3) ^ ((row >> 1) & 3);  // swizzled 16B chunk
    gA[r] = (size_t)(m0 + row) * Kb + (sc << 4);
  }
#pragma unroll
  for (int r = 0; r < RB; ++r) {
    int L = (r * 256 + tid) * 16;
    lB[r] = L;
    int row = L >> 6;
    int sc  = ((L >> 4) & 3) ^ ((row >> 1) & 3);
    gB[r] = (size_t)(n0 + row) * Kb + (sc << 4);
  }

  f32x4 acc[MT][NT] = {};
  const char* Ah = (const char*)Ahi;
  const char* Al = (const char*)Alo;
  const char* Bh = (const char*)Bhi;
  const char* Bl = (const char*)Blo;
  char* asH = (char*)AsH; char* asL = (char*)AsL;
  char* bsH = (char*)BsH; char* bsL = (char*)BsL;

  const int kIt = K / BK;

  // prologue: stage tile 0 into buffer 0 (guards are wave-uniform)
#pragma unroll
  for (int r = 0; r < RA; ++r)
    if (ABYTES % 4096 == 0 || lA[r] < ABYTES) {
      g2lds(Ah + gA[r], asH + lA[r]);
      g2lds(Al + gA[r], asL + lA[r]);
    }
#pragma unroll
  for (int r = 0; r < RB; ++r)
    if (BBYTES % 4096 == 0 || lB[r] < BBYTES) {
      g2lds(Bh + gB[r], bsH + lB[r]);
      g2lds(Bl + gB[r], bsL + lB[r]);
    }

  int cur = 0;
  for (int it = 0; it < kIt; ++it) {
    // compiler emits s_waitcnt vmcnt(0) lgkmcnt(0) before s_barrier:
    // drains buf[cur] staging loads (issued last iter, covered by compute)
    // and guarantees prior-iter ds_reads of the buffer we're about to refill.
    __syncthreads();

    if (it + 1 < kIt) {  // issue next tile's loads into the other buffer
      const size_t kadd = (size_t)(it + 1) * (BK * 2);
      const int la = (cur ^ 1) * ABYTES;
      const int lb = (cur ^ 1) * BBYTES;
#pragma unroll
      for (int r = 0; r < RA; ++r)
        if (ABYTES % 4096 == 0 || lA[r] < ABYTES) {
          g2lds(Ah + gA[r] + kadd, asH + la + lA[r]);
          g2lds(Al + gA[r] + kadd, asL + la + lA[r]);
        }
#pragma unroll
      for (int r = 0; r < RB; ++r)
        if (BBYTES % 4096 == 0 || lB[r] < BBYTES) {
          g2lds(Bh + gB[r] + kadd, bsH + lb + lB[r]);
          g2lds(Bl + gB[r] + kadd, bsL + lb + lB[r]);
        }
    }

    bf16x8 fa_h[MT], fa_l[MT], fb_h[NT], fb_l[NT];
#pragma unroll
    for (int mt = 0; mt < MT; ++mt) {
      int r = wm + mt * 16 + (lane & 15);
      int c = (lane >> 4) ^ ((r >> 1) & 3);  // swizzled chunk (matches staging)
      int off = r * BK + c * 8;
      fa_h[mt] = *(const bf16x8*)&AsH[cur][off];
      fa_l[mt] = *(const bf16x8*)&AsL[cur][off];
    }
#pragma unroll
    for (int nt = 0; nt < NT; ++nt) {
      int r = wn + nt * 16 + (lane & 15);
      int c = (lane >> 4) ^ ((r >> 1) & 3);
      int off = r * BK + c * 8;
      fb_h[nt] = *(const bf16x8*)&BsH[cur][off];
      fb_l[nt] = *(const bf16x8*)&BsL[cur][off];
    }
#pragma unroll
    for (int mt = 0; mt < MT; ++mt)
#pragma unroll
      for (int nt = 0; nt < NT; ++nt) {
        acc[mt][nt] = __builtin_amdgcn_mfma_f32_16x16x32_bf16(fa_h[mt], fb_h[nt], acc[mt][nt], 0, 0, 0);
        acc[mt][nt] = __builtin_amdgcn_mfma_f32_16x16x32_bf16(fa_l[mt], fb_h[nt], acc[mt][nt], 0, 0, 0);
        acc[mt][nt] = __builtin_amdgcn_mfma_f32_16x16x32_bf16(fa_h[mt], fb_l[nt], acc[mt][nt], 0, 0, 0);
      }
    cur ^= 1;
  }

  // epilogue: C/D layout col = lane&15, row = (lane>>4)*4 + reg  [m89-verified]
#pragma unroll
  for (int mt = 0; mt < MT; ++mt) {
    const int mb = m0 + wm + mt * 16 + ((lane >> 4) << 2);
    float a0v[4], a1v[4];
    if (EPI == 1 || EPI == 3) {
#pragma unroll
      for (int r = 0; r < 4; ++r) {
        a0v[r] = a_t[(mb + r) * 2];
        a1v[r] = a_t[(mb + r) * 2 + 1];
      }
    }
#pragma unroll
    for (int nt = 0; nt < NT; ++nt) {
      const int n = n0 + wn + nt * 16 + (lane & 15);
      const float bv = bias[n];
      float w0 = 0.f, w1 = 0.f;
      if (EPI == 1) { w0 = w1r[n]; w1 = w1r[HID + n]; }
#pragma unroll
      for (int r = 0; r < 4; ++r) {
        float v = acc[mt][nt][r] + bv;
        if (EPI == 3) {
          // pair adjacent columns: even lane holds P[b][2j], odd holds P[b][2j+1]
          float vx = __shfl_xor(v, 1);
          if (!(lane & 1)) {
            const int b = mb + r;
            const int j = n >> 1;
            const float sv = S[b * ND + j] + (v * a0v[r] + vx * a1v[r]) * 0.1f;
            S[b * ND + j] = sv;
            unsigned short h = f2bf(sv);
            Zhi[b * ND + j] = h;
            Zlo[b * ND + j] = f2bf(sv - bf2f(h));
            gen[(size_t)b * ((T_SZ + 1) * ND) + (size_t)(t + 1) * ND + j] = sv;
          }
        } else {
          if (EPI == 1) v += a0v[r] * w0 + a1v[r] * w1;
          v = fmaxf(v, 0.f);
          unsigned short h = f2bf(v);
          const size_t idx = (size_t)(mb + r) * ldc + n;
          Zhi[idx] = h;
          Zlo[idx] = f2bf(v - bf2f(h));
        }
      }
    }
  }
}

// One-time per launch: transpose+split weights (N x K bf16 hi/lo), transpose
// actions to (T, B, 2), init s = states[:,0,:], write gen[:,0,:].
__global__ void prep_kernel(
    const float* __restrict__ states, const float* __restrict__ actions,
    const float* __restrict__ W1, const float* __restrict__ W2,
    const float* __restrict__ W3,
    unsigned short* __restrict__ W1tH, unsigned short* __restrict__ W1tL,
    unsigned short* __restrict__ W2tH, unsigned short* __restrict__ W2tL,
    unsigned short* __restrict__ W3tH, unsigned short* __restrict__ W3tL,
    float* __restrict__ aT, float* __restrict__ s,
    unsigned short* __restrict__ sH, unsigned short* __restrict__ sL,
    float* __restrict__ gen) {
  const int tid = blockIdx.x * blockDim.x + threadIdx.x;
  const int stride = gridDim.x * blockDim.x;
  for (int i = tid; i < ND * HID; i += stride) {  // W1 rows 0..127 only
    int k = i >> 10, j = i & 1023;
    float v = W1[i];
    unsigned short h = f2bf(v);
    W1tH[j * ND + k] = h;
    W1tL[j * ND + k] = f2bf(v - bf2f(h));
  }
  for (int i = tid; i < HID * HID; i += stride) {
    int k = i >> 10, j = i & 1023;
    float v = W2[i];
    unsigned short h = f2bf(v);
    W2tH[j * HID + k] = h;
    W2tL[j * HID + k] = f2bf(v - bf2f(h));
  }
  for (int i = tid; i < HID * PO; i += stride) {  // W3 cols 256..511 only
    int k = i >> 8, j = i & 255;
    float v = W3[k * 512 + 256 + j];
    unsigned short h = f2bf(v);
    W3tH[j * HID + k] = h;
    W3tL[j * HID + k] = f2bf(v - bf2f(h));
  }
  for (int i = tid; i < B_SZ * T_SZ; i += stride) {  // actions (B,T,2) -> (T,B,2)
    int b = i >> 6, t = i & 63;
    float2 v = ((const float2*)actions)[i];
    ((float2*)aT)[t * B_SZ + b] = v;
  }
  for (int i = tid; i < B_SZ * ND; i += stride) {  // s0, splits, gen[:,0,:]
    int b = i >> 7, n = i & 127;
    float v = states[(size_t)b * (T_SZ * ND) + n];
    s[i] = v;
    unsigned short h = f2bf(v);
    sH[i] = h;
    sL[i] = f2bf(v - bf2f(h));
    gen[(size_t)b * ((T_SZ + 1) * ND) + n] = v;
  }
}

extern "C" void kernel_launch(void* const* d_in, const int* in_sizes, int n_in,
                              void* d_out, int out_size, void* d_ws, size_t ws_size,
                              hipStream_t stream) {
  const float* states  = (const float*)d_in[0];
  const float* actions = (const float*)d_in[1];
  const float* W1 = (const float*)d_in[2];
  const float* b1 = (const float*)d_in[3];
  const float* W2 = (const float*)d_in[4];
  const float* b2 = (const float*)d_in[5];
  const float* W3 = (const float*)d_in[6];
  const float* b3 = (const float*)d_in[7];
  float* gen = (float*)d_out;

  char* w = (char*)d_ws;
  float*          s    = (float*)(w + 0);                          // 2 MB
  unsigned short* sH   = (unsigned short*)(w + (2ull << 20));      // 1 MB
  unsigned short* sL   = (unsigned short*)(w + (3ull << 20));      // 1 MB
  unsigned short* z1H  = (unsigned short*)(w + (4ull << 20));      // 8 MB
  unsigned short* z1L  = (unsigned short*)(w + (12ull << 20));     // 8 MB
  unsigned short* z2H  = (unsigned short*)(w + (20ull << 20));     // 8 MB
  unsigned short* z2L  = (unsigned short*)(w + (28ull << 20));     // 8 MB
  float*          aT   = (float*)(w + (40ull << 20));              // 2 MB
  unsigned short* W1tH = (unsigned short*)(w + (42ull << 20));             // 256 KB
  unsigned short* W1tL = (unsigned short*)(w + (42ull << 20) + 262144);    // 256 KB
  unsigned short* W2tH = (unsigned short*)(w + (43ull << 20));             // 2 MB
  unsigned short* W2tL = (unsigned short*)(w + (45ull << 20));             // 2 MB
  unsigned short* W3tH = (unsigned short*)(w + (47ull << 20));             // 512 KB
  unsigned short* W3tL = (unsigned short*)(w + (47ull << 20) + 524288);    // 512 KB
  // total ws use: 48 MB

  prep_kernel<<<2048, 256, 0, stream>>>(states, actions, W1, W2, W3,
      W1tH, W1tL, W2tH, W2tL, W3tH, W3tL, aT, s, sH, sL, gen);

  const float* w1r = W1 + 128 * 1024;  // W1 rows 128,129 (action columns), fp32
  for (int t = 0; t < 64; ++t) {
    const float* at = aT + (size_t)t * B_SZ * 2;
    // L1: z1 = relu([s,a] @ W1 + b1)   (K=128 MFMA part + exact fp32 rank-2)
    gemm_split<128, 64, 4, 2, 1><<<dim3(32, 16), 256, 0, stream>>>(
        sH, sL, W1tH, W1tL, b1, 128, HID, at, w1r, z1H, z1L,
        (float*)nullptr, (float*)nullptr, 0);
    // L2: z2 = relu(z1 @ W2 + b2)
    gemm_split<128, 64, 4, 2, 2><<<dim3(32, 16), 256, 0, stream>>>(
        z1H, z1L, W2tH, W2tL, b2, HID, HID, (const float*)nullptr,
        (const float*)nullptr, z2H, z2L, (float*)nullptr, (float*)nullptr, 0);
    // L3 + fused state update: P = z2 @ W3[:,256:512] + b3[256:512];
    // s += (P[:,2j]*a0 + P[:,2j+1]*a1)*DT; writes s, sH, sL, gen[:,t+1,:]
    gemm_split<64, 32, 2, 1, 3><<<dim3(64, 8), 256, 0, stream>>>(
        z2H, z2L, W3tH, W3tL, b3 + 256, HID, PO, at, (const float*)nullptr,
        sH, sL, s, gen, t);
  }
}